// Round 7
// baseline (181.937 us; speedup 1.0000x reference)
//
#include <hip/hip_runtime.h>

// Problem constants (fixed by setup_inputs)
#define BB    4
#define TT    300
#define NN    200
#define NINN  100
#define KK    10
#define DECAY 0.8f
#define THR   0.6f
#define DAMP  0.3f

// Scan chunking: compile-time trip counts (full unroll, batched loads).
#define LCH   20
#define NCHK  (TT / LCH)      // 15
#define WARM  48              // 0.8^48*5 ~ 1e-4 << 0.115 threshold

// ws layout (floats)
#define XBAR_OFF  0
#define ZFILT_OFF (BB*TT*NINN)                  // 120000
#define ZBAR_OFF  (ZFILT_OFF + BB*TT*NN)        // 360000
#define CBUF_OFF  (ZBAR_OFF  + BB*TT*NN)        // 600000

// K1 thread ranges (bases multiple of 256 -> no wave straddle)
#define R_A_N     (BB*NCHK*NINN)     // 6000
#define R_B_BASE  6144
#define R_B_N     (BB*NCHK*NN)       // 12000 -> ends 18144
#define R_C_BASE  18176
#define R_C_N     (BB*NCHK*NN)       // 12000 -> ends 30176 (c-compute branch)
#define R_Z_BASE  30208
#define R_Z_N     500                // zero dw_out region (2000 floats, float4)
#define K1_TOTAL  (R_Z_BASE + R_Z_N) // 30708 -> 120 blocks

// ---------------------------------------------------------------------------
// Kernel 1 (K2 FOLDED IN): forward scans (xbar, zfilt/zbar), and the full
// c-computation: per-(b,chunk,j) thread keeps 10 reverse-filter accumulators
// Gk (one per error-output k), dots with w_out[j,:] each step, applies
// refractory mask from a register z-window, writes cbuf directly.
// ---------------------------------------------------------------------------
__global__ void scan_kernel(const float* __restrict__ v,
                            const float* __restrict__ z,
                            const float* __restrict__ x,
                            const float* __restrict__ error1,
                            const float* __restrict__ error2,
                            const float* __restrict__ w_out,
                            float* __restrict__ ws,
                            float* __restrict__ out) {
    int tid = blockIdx.x * blockDim.x + threadIdx.x;
    float* xbar  = ws + XBAR_OFF;
    float* zfilt = ws + ZFILT_OFF;
    float* zbar  = ws + ZBAR_OFF;
    float* cbuf  = ws + CBUF_OFF;

    if (tid < R_A_N) {
        // ---- xbar forward scan ----
        int i = tid % NINN, r = tid / NINN;
        int chunk = r % NCHK, b = r / NCHK;
        int t0 = chunk * LCH;
        const float* src = x + (size_t)b * TT * NINN + i;
        float acc = 0.f;
        #pragma unroll
        for (int d = WARM; d >= 1; --d) {
            int t = t0 - d;
            int tc = t < 0 ? 0 : t;
            float val = src[tc * NINN];
            acc = DECAY * acc + (t < 0 ? 0.f : val);
        }
        float vals[LCH];
        #pragma unroll
        for (int tt = 0; tt < LCH; ++tt) vals[tt] = src[(t0 + tt) * NINN];
        #pragma unroll
        for (int tt = 0; tt < LCH; ++tt) { acc = DECAY * acc + vals[tt]; vals[tt] = acc; }
        float* dst = xbar + (size_t)b * TT * NINN + i;
        #pragma unroll
        for (int tt = 0; tt < LCH; ++tt) dst[(t0 + tt) * NINN] = vals[tt];
    } else if (tid >= R_B_BASE && tid < R_B_BASE + R_B_N) {
        // ---- zfilt/zbar forward scan ----
        int u = tid - R_B_BASE;
        int j = u % NN, r = u / NN;
        int chunk = r % NCHK, b = r / NCHK;
        int t0 = chunk * LCH;
        const float* src = z + (size_t)b * TT * NN + j;
        float acc = 0.f;
        #pragma unroll
        for (int d = WARM; d >= 1; --d) {
            int t = t0 - d;
            int tc = t < 0 ? 0 : t;
            float val = src[tc * NN];
            acc = DECAY * acc + (t < 0 ? 0.f : val);
        }
        float zv[LCH], pre[LCH];
        #pragma unroll
        for (int tt = 0; tt < LCH; ++tt) zv[tt] = src[(t0 + tt) * NN];
        #pragma unroll
        for (int tt = 0; tt < LCH; ++tt) {
            pre[tt] = acc;                      // zbar[t] = zfilt[t-1]
            acc = DECAY * acc + zv[tt];
            zv[tt] = acc;                       // zfilt[t]
        }
        float* dzb = zbar  + (size_t)b * TT * NN + j;
        float* dzf = zfilt + (size_t)b * TT * NN + j;
        #pragma unroll
        for (int tt = 0; tt < LCH; ++tt) dzb[(t0 + tt) * NN] = pre[tt];
        #pragma unroll
        for (int tt = 0; tt < LCH; ++tt) dzf[(t0 + tt) * NN] = zv[tt];
    } else if (tid >= R_C_BASE && tid < R_C_BASE + R_C_N) {
        // ---- c-compute: reverse-filtered learning signal + post_term ----
        int u = tid - R_C_BASE;
        int j = u % NN, r = u / NN;
        int chunk = r % NCHK, b = r / NCHK;
        int t0 = chunk * LCH, t1 = t0 + LCH - 1;

        float wj[KK];
        #pragma unroll
        for (int k = 0; k < KK; ++k) wj[k] = w_out[j * KK + k];
        float coeff = 0.25f * error2[j];        // REG/(B*T)

        // per-k reverse filters: Gk[k][t] = e1[t,k] + 0.8*Gk[k][t+1]
        float Gk[KK];
        #pragma unroll
        for (int k = 0; k < KK; ++k) Gk[k] = 0.f;
        #pragma unroll
        for (int d = WARM; d >= 1; --d) {
            int t = t1 + d;
            int tc = t > TT - 1 ? TT - 1 : t;
            const float* e = error1 + ((size_t)b * TT + tc) * KK;
            bool oob = (t > TT - 1);
            #pragma unroll
            for (int h = 0; h < KK / 2; ++h) {
                float2 ev = *(const float2*)(e + 2 * h);
                Gk[2 * h]     = DECAY * Gk[2 * h]     + (oob ? 0.f : ev.x);
                Gk[2 * h + 1] = DECAY * Gk[2 * h + 1] + (oob ? 0.f : ev.y);
            }
        }

        // z window: zwin[q] = z[t0-4+q] (0 for t<0), covers z[t-4..t-1] needs
        float zwin[LCH + 4];
        #pragma unroll
        for (int q = 0; q < LCH + 4; ++q) {
            int s = t0 - 4 + q;
            int sc = s < 0 ? 0 : s;
            float zl = z[((size_t)b * TT + sc) * NN + j];
            zwin[q] = (s < 0) ? 0.f : zl;
        }
        float vv[LCH];
        #pragma unroll
        for (int tt = 0; tt < LCH; ++tt)
            vv[tt] = v[((size_t)b * TT + t0 + tt) * NN + j];

        #pragma unroll
        for (int tt = LCH - 1; tt >= 0; --tt) {
            int t = t0 + tt;
            const float* e = error1 + ((size_t)b * TT + t) * KK;
            #pragma unroll
            for (int h = 0; h < KK / 2; ++h) {
                float2 ev = *(const float2*)(e + 2 * h);
                Gk[2 * h]     = DECAY * Gk[2 * h]     + ev.x;
                Gk[2 * h + 1] = DECAY * Gk[2 * h + 1] + ev.y;
            }
            float L = 0.f;
            #pragma unroll
            for (int k = 0; k < KK; ++k) L += wj[k] * Gk[k];
            // refractory: spike in z[t-4..t-1] <-> zwin[tt..tt+3]
            bool refr = (zwin[tt] > 0.f) || (zwin[tt + 1] > 0.f) ||
                        (zwin[tt + 2] > 0.f) || (zwin[tt + 3] > 0.f);
            float vs = (vv[tt] - THR) / THR;
            float psi = (DAMP / THR) * fmaxf(1.f - fabsf(vs), 0.f);
            cbuf[((size_t)b * TT + t) * NN + j] = (refr ? 0.f : psi) * (L + coeff);
        }
    } else if (tid >= R_Z_BASE && tid < R_Z_BASE + R_Z_N) {
        int u = tid - R_Z_BASE;
        ((float4*)(out + NINN * NN + NN * NN))[u] = make_float4(0.f, 0.f, 0.f, 0.f);
    }
}

// ---------------------------------------------------------------------------
// Kernel 2: atomic-free blocked contraction.  [unchanged structure]
// ---------------------------------------------------------------------------
#define SKB 16
#define KC3 (BB * TT / SKB)    // 75
#define PT  4
#define JT  64

__global__ void out_kernel(const float* __restrict__ error1,
                           const float* __restrict__ ws,
                           float* __restrict__ out) {
    __shared__ float red[SKB * PT * JT];   // 16 KB
    int bid = blockIdx.x;
    int tid = threadIdx.x;
    const float* xbar  = ws + XBAR_OFF;
    const float* zfilt = ws + ZFILT_OFF;
    const float* zbar  = ws + ZBAR_OFF;
    const float* cbuf  = ws + CBUF_OFF;

    if (bid < 300) {
        int pt = bid >> 2;                 // 0..74
        int jt = bid & 3;                  // 0..3
        int p0 = pt * PT;
        int j0 = jt * JT;
        int W = NN - j0; if (W > JT) W = JT;     // 64,64,64,8
        int jq = tid & 15;
        int s  = tid >> 4;

        if (jq * 4 < W) {
            bool isrec = (p0 >= NINN);
            const float* A = isrec ? (zbar + (p0 - NINN)) : (xbar + p0);
            int lda = isrec ? NN : NINN;
            const float* C = cbuf + j0 + jq * 4;
            int bt0 = s * KC3;
            float acc[4][4];
            #pragma unroll
            for (int a = 0; a < 4; ++a)
                #pragma unroll
                for (int c = 0; c < 4; ++c) acc[a][c] = 0.f;
            #pragma unroll 5
            for (int rr = 0; rr < KC3; ++rr) {
                int bt = bt0 + rr;
                float4 av = *(const float4*)(A + (size_t)bt * lda);
                float4 cv = *(const float4*)(C + (size_t)bt * NN);
                float am[4] = {av.x, av.y, av.z, av.w};
                float cm[4] = {cv.x, cv.y, cv.z, cv.w};
                #pragma unroll
                for (int a = 0; a < 4; ++a)
                    #pragma unroll
                    for (int c = 0; c < 4; ++c) acc[a][c] += am[a] * cm[c];
            }
            float* dst = red + s * (PT * JT) + jq * 4;
            #pragma unroll
            for (int a = 0; a < 4; ++a)
                *(float4*)(dst + a * JT) =
                    make_float4(acc[a][0], acc[a][1], acc[a][2], acc[a][3]);
        }
        __syncthreads();

        int o = tid;                       // p_local*64 + j_local
        int pl = o >> 6, jl = o & 63;
        if (jl < W) {
            float sum = 0.f;
            #pragma unroll
            for (int s2 = 0; s2 < SKB; ++s2) sum += red[s2 * (PT * JT) + o];
            int row = p0 + pl;
            int j = j0 + jl;
            if (row < NINN) {
                out[row * NN + j] = sum;
            } else {
                int i = row - NINN;
                out[NINN * NN + i * NN + j] = (i == j) ? 0.f : sum;
            }
        }
    } else {
        int u = (bid - 300) * 256 + tid;
        if (u < 6 * NN * KK) {
            int jk = u % (NN * KK);
            int s = u / (NN * KK);         // 0..5
            int j = jk % NN;               // lanes -> coalesced zfilt
            int k = jk / NN;
            int bt0 = s * 200;
            float acc = 0.f;
            #pragma unroll 8
            for (int rr = 0; rr < 200; ++rr) {
                int bt = bt0 + rr;
                acc += zfilt[bt * NN + j] * error1[bt * KK + k];
            }
            atomicAdd(out + NINN * NN + NN * NN + j * KK + k, acc);
        }
    }
}

extern "C" void kernel_launch(void* const* d_in, const int* in_sizes, int n_in,
                              void* d_out, int out_size, void* d_ws, size_t ws_size,
                              hipStream_t stream) {
    const float* v  = (const float*)d_in[0];
    const float* z  = (const float*)d_in[1];
    const float* x  = (const float*)d_in[2];
    const float* e1 = (const float*)d_in[3];
    const float* e2 = (const float*)d_in[4];
    const float* wo = (const float*)d_in[5];
    float* out = (float*)d_out;
    float* ws  = (float*)d_ws;

    scan_kernel<<<(K1_TOTAL + 255) / 256, 256, 0, stream>>>(
        v, z, x, e1, e2, wo, ws, out);

    out_kernel<<<347, 256, 0, stream>>>(e1, ws, out);
}

// Round 8
// 86.976 us; speedup vs baseline: 2.0918x; 2.0918x over previous
//
#include <hip/hip_runtime.h>

// Problem constants (fixed by setup_inputs)
#define BB    4
#define TT    300
#define NN    200
#define NINN  100
#define KK    10
#define DECAY 0.8f
#define THR   0.6f
#define DAMP  0.3f

// Scan chunking: compile-time trip counts (full unroll, batched loads).
// LCH=20 measured best (R5 87.18 vs R6 LCH=10 88.6). Do NOT fuse the
// c-computation into this kernel: R7 showed it spills to scratch
// (VGPR cap 64, +22MB scratch writes, 120us).
#define LCH   20
#define NCHK  (TT / LCH)      // 15
#define WARM  48              // 0.8^48*5 ~ 1e-4 << 0.115 threshold

// ws layout (floats)
#define XBAR_OFF  0
#define ZFILT_OFF (BB*TT*NINN)                  // 120000
#define ZBAR_OFF  (ZFILT_OFF + BB*TT*NN)        // 360000
#define CBUF_OFF  (ZBAR_OFF  + BB*TT*NN)        // 600000
#define GBAR_OFF  (CBUF_OFF  + BB*TT*NN)        // 840000 (+12000)

// K1 thread ranges (bases multiple of 256 -> no wave straddle)
#define R_A_N     (BB*NCHK*NINN)     // 6000
#define R_B_BASE  6144
#define R_B_N     (BB*NCHK*NN)       // 12000
#define R_G_BASE  18176
#define R_G_N     (BB*NCHK*KK)       // 600
#define R_Z_BASE  18944
#define R_Z_N     500                // zero dw_out region (2000 floats, float4)
#define K1_TOTAL  (R_Z_BASE + R_Z_N)

// ---------------------------------------------------------------------------
// Kernel 1: forward scans (xbar, zfilt/zbar), reverse scan of error1 (Gbar),
// zero the dw_out region (for K3's small atomic tail).
// ---------------------------------------------------------------------------
__global__ void scan_kernel(const float* __restrict__ z,
                            const float* __restrict__ x,
                            const float* __restrict__ error1,
                            float* __restrict__ ws,
                            float* __restrict__ out) {
    int tid = blockIdx.x * blockDim.x + threadIdx.x;
    float* xbar  = ws + XBAR_OFF;
    float* zfilt = ws + ZFILT_OFF;
    float* zbar  = ws + ZBAR_OFF;
    float* gbar  = ws + GBAR_OFF;

    if (tid < R_A_N) {
        int i = tid % NINN, r = tid / NINN;
        int chunk = r % NCHK, b = r / NCHK;
        int t0 = chunk * LCH;
        const float* src = x + (size_t)b * TT * NINN + i;
        float acc = 0.f;
        #pragma unroll
        for (int d = WARM; d >= 1; --d) {
            int t = t0 - d;
            int tc = t < 0 ? 0 : t;
            float val = src[tc * NINN];
            acc = DECAY * acc + (t < 0 ? 0.f : val);
        }
        float vals[LCH];
        #pragma unroll
        for (int tt = 0; tt < LCH; ++tt) vals[tt] = src[(t0 + tt) * NINN];
        #pragma unroll
        for (int tt = 0; tt < LCH; ++tt) { acc = DECAY * acc + vals[tt]; vals[tt] = acc; }
        float* dst = xbar + (size_t)b * TT * NINN + i;
        #pragma unroll
        for (int tt = 0; tt < LCH; ++tt) dst[(t0 + tt) * NINN] = vals[tt];
    } else if (tid >= R_B_BASE && tid < R_B_BASE + R_B_N) {
        int u = tid - R_B_BASE;
        int j = u % NN, r = u / NN;
        int chunk = r % NCHK, b = r / NCHK;
        int t0 = chunk * LCH;
        const float* src = z + (size_t)b * TT * NN + j;
        float acc = 0.f;
        #pragma unroll
        for (int d = WARM; d >= 1; --d) {
            int t = t0 - d;
            int tc = t < 0 ? 0 : t;
            float val = src[tc * NN];
            acc = DECAY * acc + (t < 0 ? 0.f : val);
        }
        float zv[LCH], pre[LCH];
        #pragma unroll
        for (int tt = 0; tt < LCH; ++tt) zv[tt] = src[(t0 + tt) * NN];
        #pragma unroll
        for (int tt = 0; tt < LCH; ++tt) {
            pre[tt] = acc;                      // zbar[t] = zfilt[t-1]
            acc = DECAY * acc + zv[tt];
            zv[tt] = acc;                       // zfilt[t]
        }
        float* dzb = zbar  + (size_t)b * TT * NN + j;
        float* dzf = zfilt + (size_t)b * TT * NN + j;
        #pragma unroll
        for (int tt = 0; tt < LCH; ++tt) dzb[(t0 + tt) * NN] = pre[tt];
        #pragma unroll
        for (int tt = 0; tt < LCH; ++tt) dzf[(t0 + tt) * NN] = zv[tt];
    } else if (tid >= R_G_BASE && tid < R_G_BASE + R_G_N) {
        int u = tid - R_G_BASE;
        int k = u % KK, r = u / KK;
        int chunk = r % NCHK, b = r / NCHK;
        int t0 = chunk * LCH, t1 = t0 + LCH - 1;
        const float* src = error1 + (size_t)b * TT * KK + k;
        float G = 0.f;
        #pragma unroll
        for (int d = WARM; d >= 1; --d) {
            int t = t1 + d;
            int tc = t > TT - 1 ? TT - 1 : t;
            float val = src[tc * KK];
            G = DECAY * G + (t > TT - 1 ? 0.f : val);
        }
        float ev[LCH];
        #pragma unroll
        for (int tt = 0; tt < LCH; ++tt) ev[tt] = src[(t1 - tt) * KK];
        float* dst = gbar + (size_t)b * TT * KK + k;
        #pragma unroll
        for (int tt = 0; tt < LCH; ++tt) {
            G = DECAY * G + ev[tt];             // Gbar[t] = e[t] + 0.8*Gbar[t+1]
            dst[(t1 - tt) * KK] = G;
        }
    } else if (tid >= R_Z_BASE && tid < R_Z_BASE + R_Z_N) {
        int u = tid - R_Z_BASE;
        ((float4*)(out + NINN * NN + NN * NN))[u] = make_float4(0.f, 0.f, 0.f, 0.f);
    }
}

// ---------------------------------------------------------------------------
// Kernel 2: one thread per (bt, 4-wide j), all float4.
// c[bt,j] = post_term * (sum_k Gbar[bt,k]*w_out[j,k] + 0.25*error2[j]).
// ---------------------------------------------------------------------------
__global__ void c_kernel(const float* __restrict__ v,
                         const float* __restrict__ z,
                         const float* __restrict__ error2,
                         const float* __restrict__ w_out,
                         float* __restrict__ ws) {
    int tid = blockIdx.x * blockDim.x + threadIdx.x;
    if (tid >= BB * TT * NN / 4) return;        // 60000
    const float* gbar = ws + GBAR_OFF;
    float* cbuf = ws + CBUF_OFF;

    int jq = tid % (NN / 4), bt = tid / (NN / 4);
    int j0 = jq * 4;
    int t = bt % TT, b = bt / TT;

    float g[KK];
    #pragma unroll
    for (int k = 0; k < KK; ++k) g[k] = gbar[bt * KK + k];

    float Ld[4];
    #pragma unroll
    for (int a = 0; a < 4; ++a) {
        const float* wr = w_out + (j0 + a) * KK;
        float acc = 0.f;
        #pragma unroll
        for (int k = 0; k < KK; ++k) acc += g[k] * wr[k];
        Ld[a] = acc;
    }

    float4 e2 = *(const float4*)(error2 + j0);
    float co[4] = {0.25f * e2.x, 0.25f * e2.y, 0.25f * e2.z, 0.25f * e2.w};

    bool refr[4] = {false, false, false, false};
    #pragma unroll
    for (int d = 1; d <= 4; ++d) {
        int s = t - d;
        int sc = s < 0 ? 0 : s;
        float4 zv = *(const float4*)(z + ((size_t)b * TT + sc) * NN + j0);
        if (s >= 0) {
            if (zv.x > 0.f) refr[0] = true;
            if (zv.y > 0.f) refr[1] = true;
            if (zv.z > 0.f) refr[2] = true;
            if (zv.w > 0.f) refr[3] = true;
        }
    }

    float4 vv = *(const float4*)(v + (size_t)bt * NN + j0);
    float vm[4] = {vv.x, vv.y, vv.z, vv.w};
    float cm[4];
    #pragma unroll
    for (int a = 0; a < 4; ++a) {
        float vs = (vm[a] - THR) / THR;
        float psi = (DAMP / THR) * fmaxf(1.f - fabsf(vs), 0.f);
        cm[a] = (refr[a] ? 0.f : psi) * (Ld[a] + co[a]);
    }
    *(float4*)(cbuf + (size_t)bt * NN + j0) = make_float4(cm[0], cm[1], cm[2], cm[3]);
}

// ---------------------------------------------------------------------------
// Kernel 3: atomic-free blocked contraction.
//   Blocks 0..299: output tile 4p x 64j; 16 K-groups x 16 jq; LDS reduce;
//   coalesced direct store (rec diagonal stored as 0).
//   Blocks 300..346: dw_out, split-K=6 atomics into zeroed region.
// ---------------------------------------------------------------------------
#define SKB 16
#define KC3 (BB * TT / SKB)    // 75
#define PT  4
#define JT  64

__global__ void out_kernel(const float* __restrict__ error1,
                           const float* __restrict__ ws,
                           float* __restrict__ out) {
    __shared__ float red[SKB * PT * JT];   // 16 KB
    int bid = blockIdx.x;
    int tid = threadIdx.x;
    const float* xbar  = ws + XBAR_OFF;
    const float* zfilt = ws + ZFILT_OFF;
    const float* zbar  = ws + ZBAR_OFF;
    const float* cbuf  = ws + CBUF_OFF;

    if (bid < 300) {
        int pt = bid >> 2;                 // 0..74
        int jt = bid & 3;                  // 0..3
        int p0 = pt * PT;
        int j0 = jt * JT;
        int W = NN - j0; if (W > JT) W = JT;     // 64,64,64,8
        int jq = tid & 15;
        int s  = tid >> 4;

        if (jq * 4 < W) {
            bool isrec = (p0 >= NINN);
            const float* A = isrec ? (zbar + (p0 - NINN)) : (xbar + p0);
            int lda = isrec ? NN : NINN;
            const float* C = cbuf + j0 + jq * 4;
            int bt0 = s * KC3;
            float acc[4][4];
            #pragma unroll
            for (int a = 0; a < 4; ++a)
                #pragma unroll
                for (int c = 0; c < 4; ++c) acc[a][c] = 0.f;
            #pragma unroll 5
            for (int rr = 0; rr < KC3; ++rr) {
                int bt = bt0 + rr;
                float4 av = *(const float4*)(A + (size_t)bt * lda);
                float4 cv = *(const float4*)(C + (size_t)bt * NN);
                float am[4] = {av.x, av.y, av.z, av.w};
                float cm[4] = {cv.x, cv.y, cv.z, cv.w};
                #pragma unroll
                for (int a = 0; a < 4; ++a)
                    #pragma unroll
                    for (int c = 0; c < 4; ++c) acc[a][c] += am[a] * cm[c];
            }
            float* dst = red + s * (PT * JT) + jq * 4;
            #pragma unroll
            for (int a = 0; a < 4; ++a)
                *(float4*)(dst + a * JT) =
                    make_float4(acc[a][0], acc[a][1], acc[a][2], acc[a][3]);
        }
        __syncthreads();

        int o = tid;                       // p_local*64 + j_local
        int pl = o >> 6, jl = o & 63;
        if (jl < W) {
            float sum = 0.f;
            #pragma unroll
            for (int s2 = 0; s2 < SKB; ++s2) sum += red[s2 * (PT * JT) + o];
            int row = p0 + pl;
            int j = j0 + jl;
            if (row < NINN) {
                out[row * NN + j] = sum;
            } else {
                int i = row - NINN;
                out[NINN * NN + i * NN + j] = (i == j) ? 0.f : sum;
            }
        }
    } else {
        int u = (bid - 300) * 256 + tid;
        if (u < 6 * NN * KK) {
            int jk = u % (NN * KK);
            int s = u / (NN * KK);         // 0..5
            int j = jk % NN;               // lanes -> coalesced zfilt
            int k = jk / NN;
            int bt0 = s * 200;
            float acc = 0.f;
            #pragma unroll 8
            for (int rr = 0; rr < 200; ++rr) {
                int bt = bt0 + rr;
                acc += zfilt[bt * NN + j] * error1[bt * KK + k];
            }
            atomicAdd(out + NINN * NN + NN * NN + j * KK + k, acc);
        }
    }
}

extern "C" void kernel_launch(void* const* d_in, const int* in_sizes, int n_in,
                              void* d_out, int out_size, void* d_ws, size_t ws_size,
                              hipStream_t stream) {
    const float* v  = (const float*)d_in[0];
    const float* z  = (const float*)d_in[1];
    const float* x  = (const float*)d_in[2];
    const float* e1 = (const float*)d_in[3];
    const float* e2 = (const float*)d_in[4];
    const float* wo = (const float*)d_in[5];
    float* out = (float*)d_out;
    float* ws  = (float*)d_ws;

    scan_kernel<<<(K1_TOTAL + 255) / 256, 256, 0, stream>>>(z, x, e1, ws, out);

    c_kernel<<<(BB * TT * NN / 4 + 255) / 256, 256, 0, stream>>>(v, z, e2, wo, ws);

    out_kernel<<<347, 256, 0, stream>>>(e1, ws, out);
}